// Round 18
// baseline (209.690 us; speedup 1.0000x reference)
//
#include <hip/hip_runtime.h>
#include <hip/hip_fp16.h>
#include <math.h>

#define N_IN_F 28
#define N_HID 16
#define NPB 256              // nodes per dst-bucket (bucket = dst >> 8)
#define NBK 1024             // bucket table size (782 actual)
#define EPB 8192             // edges per chunk (bhist/bin blocks)
#define SRC_BITS 18
#define SRC_MASK ((1 << SRC_BITS) - 1)
#define STAGE_CAP 10240      // LDS stage entries for k_sort2 (bucket mean 8192, sigma ~90)

// ---------------- build: chunk histograms -> column scans -> staged bin -> staged sort+h1 ----------------

// chunk histogram of dst>>8, saved to global (u16, coalesced). No global atomics.
__global__ void __launch_bounds__(512)
k_bhist(const int* __restrict__ dst, unsigned short* __restrict__ chunk_hist, int ne) {
    __shared__ int hist[NBK];
    int tid = threadIdx.x;
    for (int t = tid; t < NBK; t += 512) hist[t] = 0;
    __syncthreads();
    int e0 = blockIdx.x * EPB;
    int e1 = min(e0 + EPB, ne);
    for (int e = e0 + tid; e < e1; e += 512) atomicAdd(&hist[dst[e] >> 8], 1);
    __syncthreads();
    unsigned short* ch = chunk_hist + (size_t)blockIdx.x * NBK;
    for (int t = tid; t < NBK; t += 512) ch[t] = (unsigned short)hist[t];
}

// 64 blocks x 16 buckets: per-bucket exclusive scan across chunks -> gdelta[chunk][bucket],
// plus per-bucket totals.
__global__ void __launch_bounds__(256)
k_colscan(const unsigned short* __restrict__ chunk_hist, int* __restrict__ gdelta,
          int* __restrict__ total, int nchunk) {
    __shared__ int p[16][17];
    int tid = threadIdx.x;
    int j = tid & 15;              // bucket lane within block's 16 buckets
    int g = tid >> 4;              // chunk-group
    int bkt = blockIdx.x * 16 + j;
    int cpg = (nchunk + 15) >> 4;
    int c0 = g * cpg, c1 = min(c0 + cpg, nchunk);

    int s = 0;
    for (int c = c0; c < c1; ++c) s += chunk_hist[(size_t)c * NBK + bkt];
    p[g][j] = s;
    __syncthreads();

    if (tid < 16) {                // serial scan over 16 groups for bucket tid
        int run = 0;
#pragma unroll
        for (int gg = 0; gg < 16; ++gg) { int t = p[gg][tid]; p[gg][tid] = run; run += t; }
        total[blockIdx.x * 16 + tid] = run;
    }
    __syncthreads();

    int run = p[g][j];
    for (int c = c0; c < c1; ++c) {
        int h = chunk_hist[(size_t)c * NBK + bkt];
        gdelta[(size_t)c * NBK + bkt] = run;
        run += h;
    }
}

// single block of 1024: exclusive scan of total -> base (+ sentinel)
__global__ void k_top(const int* __restrict__ total, int* __restrict__ base, int ne) {
    __shared__ int sm[NBK];
    int tid = threadIdx.x;
    int v = total[tid];
    sm[tid] = v;
    __syncthreads();
    for (int off = 1; off < NBK; off <<= 1) {
        int t = (tid >= off) ? sm[tid - off] : 0;
        __syncthreads();
        sm[tid] += t;
        __syncthreads();
    }
    base[tid] = sm[tid] - v;
    if (tid == 0) base[NBK] = ne;
}

// staged bin, 1024 threads (1 bucket/thread, 8 edges/thread): positions precomputed,
// wave-shuffle scan (3 barriers), 4B stage + u16 sbid side-table (O(1) write-out).
__global__ void __launch_bounds__(1024)
k_bin(const int* __restrict__ src, const int* __restrict__ dst,
      const unsigned short* __restrict__ chunk_hist, const int* __restrict__ gdelta,
      const int* __restrict__ base, int* __restrict__ binned, int ne) {
    __shared__ int gpos[NBK];
    __shared__ int lcur[NBK];
    __shared__ int wpart[16];
    __shared__ int stage[EPB];               // 32 KB
    __shared__ unsigned short sbid[EPB];     // 16 KB
    int tid = threadIdx.x;
    int lane = tid & 63;
    int wid = tid >> 6;                      // 0..15
    int chunk = blockIdx.x;

    // one bucket per thread: load hist value, block-scan via wave shuffles
    int h = chunk_hist[(size_t)chunk * NBK + tid];
    int val = h;
#pragma unroll
    for (int off = 1; off < 64; off <<= 1) {
        int t = __shfl_up(val, off, 64);
        if (lane >= off) val += t;
    }
    if (lane == 63) wpart[wid] = val;
    __syncthreads();
    if (wid == 0) {
        int p = (lane < 16) ? wpart[lane] : 0;
#pragma unroll
        for (int off = 1; off < 16; off <<= 1) {
            int t = __shfl_up(p, off, 64);
            if (lane >= off) p += t;
        }
        if (lane < 16) wpart[lane] = p;      // inclusive over waves
    }
    __syncthreads();
    int wbase = (wid > 0) ? wpart[wid - 1] : 0;
    int excl = wbase + val - h;              // exclusive prefix = local base
    gpos[tid] = base[tid] + gdelta[(size_t)chunk * NBK + tid] - excl;
    lcur[tid] = excl;
    __syncthreads();

    int e0 = chunk * EPB;
    int csz = min(EPB, ne - e0);

    // local scatter into LDS stage (bucket-sorted within chunk), 4B + 2B per edge
    for (int i = tid; i < csz; i += 1024) {
        int d = dst[e0 + i];
        int b = d >> 8;
        int r = atomicAdd(&lcur[b], 1);
        stage[r] = src[e0 + i] | ((d & (NPB - 1)) << SRC_BITS);
        sbid[r] = (unsigned short)b;
    }
    __syncthreads();

    // coalesced write-out: O(1) bucket lookup via sbid
    for (int i = tid; i < csz; i += 1024) {
        binned[gpos[sbid[i]] + i] = stage[i];
    }
}

// block per dst-bucket: counting sort by dst-local index, STAGED in LDS for coalesced
// write-out -> node-contiguous binned2 (plain src), row_start[], dis[];
// FUSED h1: hs1 = fp16((x@W1)*dis), one interleaved 32B row per node.
__global__ void __launch_bounds__(512)
k_sort2(const int* __restrict__ base, const int* __restrict__ binned,
        int* __restrict__ binned2, int* __restrict__ row_start,
        float* __restrict__ dis, const float* __restrict__ x,
        const float* __restrict__ W1, __half* __restrict__ hs1,
        int n, int nb_total) {
    __shared__ int cnt[NPB];
    __shared__ int pos[NPB];
    __shared__ int cur[NPB];
    __shared__ float w[N_IN_F * N_HID];
    __shared__ int stage[STAGE_CAP];
    int tid = threadIdx.x;
    if (tid < NPB) cnt[tid] = 0;
    for (int t = tid; t < N_IN_F * N_HID; t += 512) w[t] = W1[t];
    __syncthreads();

    int b = blockIdx.x;
    int e0 = base[b], e1 = base[b + 1];
    int csz = e1 - e0;

    for (int e = e0 + tid; e < e1; e += 512) atomicAdd(&cnt[binned[e] >> SRC_BITS], 1);
    __syncthreads();

    int v = (tid < NPB) ? cnt[tid] : 0;
    if (tid < NPB) pos[tid] = v;
    __syncthreads();
    for (int off = 1; off < NPB; off <<= 1) {
        int t = (tid < NPB && tid >= off) ? pos[tid - off] : 0;
        __syncthreads();
        if (tid < NPB) pos[tid] += t;
        __syncthreads();
    }
    if (tid < NPB) {
        int excl = pos[tid] - v;           // exclusive prefix within bucket
        cur[tid] = excl;                   // stage-local cursor
        int g = b * NPB + tid;
        if (g < n) {
            row_start[g] = e0 + excl;
            dis[g] = rsqrtf((float)(v + 1));   // in-degree + self-loop
        }
    }
    if (b == nb_total - 1 && tid == 0) row_start[n] = e1;
    __syncthreads();

    // scatter into LDS stage (node-sorted within bucket); overflow -> direct store
    for (int e = e0 + tid; e < e1; e += 512) {
        int p = binned[e];
        int r = atomicAdd(&cur[p >> SRC_BITS], 1);
        int val = p & SRC_MASK;
        if (r < STAGE_CAP) stage[r] = val;
        else binned2[e0 + r] = val;
    }
    __syncthreads();

    // coalesced write-out
    int lim = min(csz, STAGE_CAP);
    for (int i = tid; i < lim; i += 512) binned2[e0 + i] = stage[i];

    // fused h1 for this bucket's 256 nodes (thread = node, tid < NPB)
    if (tid < NPB) {
        int g = b * NPB + tid;
        if (g < n) {
            float di = rsqrtf((float)(cnt[tid] + 1));
            float xi[N_IN_F];
            const float4* xr = (const float4*)(x + (size_t)g * N_IN_F);
#pragma unroll
            for (int q = 0; q < N_IN_F / 4; ++q) {
                float4 vv = xr[q];
                xi[4 * q + 0] = vv.x; xi[4 * q + 1] = vv.y;
                xi[4 * q + 2] = vv.z; xi[4 * q + 3] = vv.w;
            }
            __half2 hp[N_HID / 2];
#pragma unroll
            for (int f2 = 0; f2 < N_HID / 2; ++f2) {
                float ha = 0.0f, hb = 0.0f;
#pragma unroll
                for (int k = 0; k < N_IN_F; ++k) {
                    ha = fmaf(xi[k], w[k * N_HID + 2 * f2], ha);
                    hb = fmaf(xi[k], w[k * N_HID + 2 * f2 + 1], hb);
                }
                hp[f2] = __floats2half2_rn(ha * di, hb * di);
            }
            int4* dstp = (int4*)(hs1 + (size_t)g * N_HID);
            dstp[0] = *(const int4*)&hp[0];
            dstp[1] = *(const int4*)&hp[4];
        }
    }
}

// ---------------- compute ----------------

// SINGLE-PASS aggregation: 8 lanes per node (half2 per lane), 16-deep unrolled gather,
// nontemporal esrc stream; fused relu + W2 + cross-lane reduce -> hs2 (fp32).
__global__ void __launch_bounds__(256)
k_agg1(const int* __restrict__ row_start, const int* __restrict__ esrc,
       const __half2* __restrict__ hs1, const float* __restrict__ dis,
       const float* __restrict__ b1, const float* __restrict__ W2,
       float2* __restrict__ hs2, int n) {
    int t = blockIdx.x * blockDim.x + threadIdx.x;
    int node = t >> 3;
    int f2 = t & 7;
    if (node >= n) return;

    int beg = row_start[node];
    int end = row_start[node + 1];
    const __half2* H = hs1 + f2;           // H[s*8] = features {2f2,2f2+1} of node s

    float2 sl = __half22float2(H[node * 8]);   // self-loop seed
    float ax = sl.x, ay = sl.y;
    float a0x = 0.f, a0y = 0.f, a1x = 0.f, a1y = 0.f;
    float a2x = 0.f, a2y = 0.f, a3x = 0.f, a3y = 0.f;
    int j = beg;
    for (; j + 16 <= end; j += 16) {
        int s[16];
#pragma unroll
        for (int q = 0; q < 16; ++q) s[q] = __builtin_nontemporal_load(&esrc[j + q]);
        float2 v[16];
#pragma unroll
        for (int q = 0; q < 16; ++q) v[q] = __half22float2(H[s[q] * 8]);
#pragma unroll
        for (int q = 0; q < 16; q += 4) {
            a0x += v[q + 0].x; a0y += v[q + 0].y;
            a1x += v[q + 1].x; a1y += v[q + 1].y;
            a2x += v[q + 2].x; a2y += v[q + 2].y;
            a3x += v[q + 3].x; a3y += v[q + 3].y;
        }
    }
    for (; j + 4 <= end; j += 4) {
        int s0 = __builtin_nontemporal_load(&esrc[j]);
        int s1 = __builtin_nontemporal_load(&esrc[j + 1]);
        int s2 = __builtin_nontemporal_load(&esrc[j + 2]);
        int s3 = __builtin_nontemporal_load(&esrc[j + 3]);
        float2 v0 = __half22float2(H[s0 * 8]);
        float2 v1 = __half22float2(H[s1 * 8]);
        float2 v2 = __half22float2(H[s2 * 8]);
        float2 v3 = __half22float2(H[s3 * 8]);
        a0x += v0.x; a0y += v0.y; a1x += v1.x; a1y += v1.y;
        a2x += v2.x; a2y += v2.y; a3x += v3.x; a3y += v3.y;
    }
    for (; j < end; ++j) {
        float2 v0 = __half22float2(H[__builtin_nontemporal_load(&esrc[j]) * 8]);
        ax += v0.x; ay += v0.y;
    }
    ax += (a0x + a1x) + (a2x + a3x);
    ay += (a0y + a1y) + (a2y + a3y);

    float di = dis[node];
    float vx = fmaxf(fmaf(di, ax, b1[2 * f2 + 0]), 0.0f);
    float vy = fmaxf(fmaf(di, ay, b1[2 * f2 + 1]), 0.0f);
    float c0 = vx * W2[4 * f2 + 0] + vy * W2[4 * f2 + 2];
    float c1 = vx * W2[4 * f2 + 1] + vy * W2[4 * f2 + 3];
#pragma unroll
    for (int off = 4; off > 0; off >>= 1) {
        c0 += __shfl_xor(c0, off, 8);
        c1 += __shfl_xor(c1, off, 8);
    }
    if (f2 == 0) {
        float2 o;
        o.x = c0 * di;
        o.y = c1 * di;
        hs2[node] = o;
    }
}

// 4 lanes per node, 8-deep batched gather of hs2 (float2, L2-resident) + fused log_softmax
__global__ void __launch_bounds__(256)
k_agg2(const int* __restrict__ row_start, const int* __restrict__ esrc,
       const float2* __restrict__ hs2, const float* __restrict__ dis,
       const float* __restrict__ b2, float2* __restrict__ out, int n) {
    int t = blockIdx.x * blockDim.x + threadIdx.x;
    int node = t >> 2;
    int l = t & 3;
    if (node >= n) return;

    int beg = row_start[node];
    int end = row_start[node + 1];
    float cx = 0.f, cy = 0.f;
    int j = beg + l;
    for (; j + 28 < end; j += 32) {       // 8 indices: j, j+4, ..., j+28
        int s[8];
#pragma unroll
        for (int q = 0; q < 8; ++q) s[q] = __builtin_nontemporal_load(&esrc[j + 4 * q]);
        float2 v[8];
#pragma unroll
        for (int q = 0; q < 8; ++q) v[q] = hs2[s[q]];
#pragma unroll
        for (int q = 0; q < 8; ++q) { cx += v[q].x; cy += v[q].y; }
    }
    for (; j < end; j += 4) {
        float2 v = hs2[__builtin_nontemporal_load(&esrc[j])];
        cx += v.x; cy += v.y;
    }
#pragma unroll
    for (int off = 2; off > 0; off >>= 1) {
        cx += __shfl_xor(cx, off, 4);
        cy += __shfl_xor(cy, off, 4);
    }
    if (l == 0) {
        float2 self = hs2[node];
        float di = dis[node];
        float a = fmaf(di, cx + self.x, b2[0]);
        float c = fmaf(di, cy + self.y, b2[1]);
        float m = fmaxf(a, c);
        float lse = m + logf(expf(a - m) + expf(c - m));
        float2 o;
        o.x = a - lse;
        o.y = c - lse;
        out[node] = o;
    }
}

// ---------------- launch ----------------

extern "C" void kernel_launch(void* const* d_in, const int* in_sizes, int n_in,
                              void* d_out, int out_size, void* d_ws, size_t ws_size,
                              hipStream_t stream) {
    const float* x  = (const float*)d_in[0];
    const int*   ei = (const int*)d_in[1];
    const float* W1 = (const float*)d_in[2];
    const float* b1 = (const float*)d_in[3];
    const float* W2 = (const float*)d_in[4];
    const float* b2 = (const float*)d_in[5];
    float2* out = (float2*)d_out;

    const int n  = in_sizes[0] / N_IN_F;   // 200000
    const int ne = in_sizes[1] / 2;        // 6400000
    const int* src = ei;
    const int* dst = ei + ne;
    const int nb = (n + NPB - 1) / NPB;    // 782 <= 1024
    const int nchunk = (ne + EPB - 1) / EPB;  // 782

    // workspace layout (4B units), total ~60MB. Aliasing (ordering-safe):
    //   gdelta (nchunk*NBK ints) aliases binned2 (dead before k_sort2 writes binned2)
    //   chunk_hist, hs1 are STANDALONE
    int* ws_i = (int*)d_ws;
    int* total     = ws_i;                      // 1024
    int* base      = total + 1024;              // 1028 (NBK+1 used)
    int* row_start = base + 1028;               // n+4
    float* dis     = (float*)(row_start + n + 4);  // n
    float2* hs2    = (float2*)(dis + n);        // n float2 (2n floats)
    __half* hs1    = (__half*)(hs2 + n);        // 16n halfs = 8n ints
    unsigned short* chunk_hist = (unsigned short*)((int*)hs1 + 8 * (size_t)n);  // nchunk*NBK u16
    int* binned2   = (int*)chunk_hist + ((size_t)nchunk * NBK + 1) / 2;  // ne
    int* binned    = binned2 + ne;              // ne
    int* gdelta    = binned2;                   // alias (nchunk*NBK ints <= ne)

    const int B = 256;

    k_bhist<<<dim3(nchunk), dim3(512), 0, stream>>>(dst, chunk_hist, ne);
    k_colscan<<<dim3(NBK / 16), dim3(B), 0, stream>>>(chunk_hist, gdelta, total, nchunk);
    k_top<<<dim3(1), dim3(NBK), 0, stream>>>(total, base, ne);
    k_bin<<<dim3(nchunk), dim3(1024), 0, stream>>>(src, dst, chunk_hist, gdelta, base, binned, ne);
    k_sort2<<<dim3(nb), dim3(512), 0, stream>>>(base, binned, binned2, row_start, dis,
                                                x, W1, hs1, n, nb);
    {
        long long tot = (long long)n * 8;
        k_agg1<<<dim3((unsigned)((tot + B - 1) / B)), dim3(B), 0, stream>>>(
            row_start, binned2, (const __half2*)hs1, dis, b1, W2, hs2, n);
    }
    {
        long long tot = (long long)n * 4;
        k_agg2<<<dim3((unsigned)((tot + B - 1) / B)), dim3(B), 0, stream>>>(
            row_start, binned2, hs2, dis, b2, out, n);
    }
}

// Round 19
// 180.326 us; speedup vs baseline: 1.1628x; 1.1628x over previous
//
#include <hip/hip_runtime.h>
#include <hip/hip_fp16.h>
#include <math.h>

#define N_IN_F 28
#define N_HID 16
#define NPB 256              // nodes per dst-bucket (bucket = dst >> 8)
#define NBK 1024             // bucket table size (782 actual)
#define EPB 8192             // edges per chunk (bhist/bin blocks)
#define SRC_BITS 18
#define SRC_MASK ((1 << SRC_BITS) - 1)
#define STAGE_CAP 10240      // LDS stage entries for k_sort2 (bucket mean 8192, sigma ~90)

// ---------------- build: chunk histograms -> column scans -> staged bin -> staged sort+h1 ----------------

// chunk histogram of dst>>8, saved to global (u16, coalesced). No global atomics.
__global__ void __launch_bounds__(512)
k_bhist(const int* __restrict__ dst, unsigned short* __restrict__ chunk_hist, int ne) {
    __shared__ int hist[NBK];
    int tid = threadIdx.x;
    for (int t = tid; t < NBK; t += 512) hist[t] = 0;
    __syncthreads();
    int e0 = blockIdx.x * EPB;
    int e1 = min(e0 + EPB, ne);
    for (int e = e0 + tid; e < e1; e += 512) atomicAdd(&hist[dst[e] >> 8], 1);
    __syncthreads();
    unsigned short* ch = chunk_hist + (size_t)blockIdx.x * NBK;
    for (int t = tid; t < NBK; t += 512) ch[t] = (unsigned short)hist[t];
}

// 64 blocks x 16 buckets: per-bucket exclusive scan across chunks -> gdelta[chunk][bucket],
// plus per-bucket totals.
__global__ void __launch_bounds__(256)
k_colscan(const unsigned short* __restrict__ chunk_hist, int* __restrict__ gdelta,
          int* __restrict__ total, int nchunk) {
    __shared__ int p[16][17];
    int tid = threadIdx.x;
    int j = tid & 15;              // bucket lane within block's 16 buckets
    int g = tid >> 4;              // chunk-group
    int bkt = blockIdx.x * 16 + j;
    int cpg = (nchunk + 15) >> 4;
    int c0 = g * cpg, c1 = min(c0 + cpg, nchunk);

    int s = 0;
    for (int c = c0; c < c1; ++c) s += chunk_hist[(size_t)c * NBK + bkt];
    p[g][j] = s;
    __syncthreads();

    if (tid < 16) {                // serial scan over 16 groups for bucket tid
        int run = 0;
#pragma unroll
        for (int gg = 0; gg < 16; ++gg) { int t = p[gg][tid]; p[gg][tid] = run; run += t; }
        total[blockIdx.x * 16 + tid] = run;
    }
    __syncthreads();

    int run = p[g][j];
    for (int c = c0; c < c1; ++c) {
        int h = chunk_hist[(size_t)c * NBK + bkt];
        gdelta[(size_t)c * NBK + bkt] = run;
        run += h;
    }
}

// single block of 1024: exclusive scan of total -> base (+ sentinel)
__global__ void k_top(const int* __restrict__ total, int* __restrict__ base, int ne) {
    __shared__ int sm[NBK];
    int tid = threadIdx.x;
    int v = total[tid];
    sm[tid] = v;
    __syncthreads();
    for (int off = 1; off < NBK; off <<= 1) {
        int t = (tid >= off) ? sm[tid - off] : 0;
        __syncthreads();
        sm[tid] += t;
        __syncthreads();
    }
    base[tid] = sm[tid] - v;
    if (tid == 0) base[NBK] = ne;
}

// staged bin, 1024 threads (1 bucket/thread, 8 edges/thread): positions precomputed,
// wave-shuffle scan (3 barriers), 4B stage + u16 sbid side-table (O(1) write-out).
__global__ void __launch_bounds__(1024)
k_bin(const int* __restrict__ src, const int* __restrict__ dst,
      const unsigned short* __restrict__ chunk_hist, const int* __restrict__ gdelta,
      const int* __restrict__ base, int* __restrict__ binned, int ne) {
    __shared__ int gpos[NBK];
    __shared__ int lcur[NBK];
    __shared__ int wpart[16];
    __shared__ int stage[EPB];               // 32 KB
    __shared__ unsigned short sbid[EPB];     // 16 KB
    int tid = threadIdx.x;
    int lane = tid & 63;
    int wid = tid >> 6;                      // 0..15
    int chunk = blockIdx.x;

    // one bucket per thread: load hist value, block-scan via wave shuffles
    int h = chunk_hist[(size_t)chunk * NBK + tid];
    int val = h;
#pragma unroll
    for (int off = 1; off < 64; off <<= 1) {
        int t = __shfl_up(val, off, 64);
        if (lane >= off) val += t;
    }
    if (lane == 63) wpart[wid] = val;
    __syncthreads();
    if (wid == 0) {
        int p = (lane < 16) ? wpart[lane] : 0;
#pragma unroll
        for (int off = 1; off < 16; off <<= 1) {
            int t = __shfl_up(p, off, 64);
            if (lane >= off) p += t;
        }
        if (lane < 16) wpart[lane] = p;      // inclusive over waves
    }
    __syncthreads();
    int wbase = (wid > 0) ? wpart[wid - 1] : 0;
    int excl = wbase + val - h;              // exclusive prefix = local base
    gpos[tid] = base[tid] + gdelta[(size_t)chunk * NBK + tid] - excl;
    lcur[tid] = excl;
    __syncthreads();

    int e0 = chunk * EPB;
    int csz = min(EPB, ne - e0);

    // local scatter into LDS stage (bucket-sorted within chunk), 4B + 2B per edge
    for (int i = tid; i < csz; i += 1024) {
        int d = dst[e0 + i];
        int b = d >> 8;
        int r = atomicAdd(&lcur[b], 1);
        stage[r] = src[e0 + i] | ((d & (NPB - 1)) << SRC_BITS);
        sbid[r] = (unsigned short)b;
    }
    __syncthreads();

    // coalesced write-out: O(1) bucket lookup via sbid
    for (int i = tid; i < csz; i += 1024) {
        binned[gpos[sbid[i]] + i] = stage[i];
    }
}

// block per dst-bucket: counting sort by dst-local index, STAGED in LDS for coalesced
// write-out -> node-contiguous binned2 (plain src), row_start[], dis[];
// FUSED h1: hs1 = fp16((x@W1)*dis), one interleaved 32B row per node.
__global__ void __launch_bounds__(512)
k_sort2(const int* __restrict__ base, const int* __restrict__ binned,
        int* __restrict__ binned2, int* __restrict__ row_start,
        float* __restrict__ dis, const float* __restrict__ x,
        const float* __restrict__ W1, __half* __restrict__ hs1,
        int n, int nb_total) {
    __shared__ int cnt[NPB];
    __shared__ int pos[NPB];
    __shared__ int cur[NPB];
    __shared__ float w[N_IN_F * N_HID];
    __shared__ int stage[STAGE_CAP];
    int tid = threadIdx.x;
    if (tid < NPB) cnt[tid] = 0;
    for (int t = tid; t < N_IN_F * N_HID; t += 512) w[t] = W1[t];
    __syncthreads();

    int b = blockIdx.x;
    int e0 = base[b], e1 = base[b + 1];
    int csz = e1 - e0;

    for (int e = e0 + tid; e < e1; e += 512) atomicAdd(&cnt[binned[e] >> SRC_BITS], 1);
    __syncthreads();

    int v = (tid < NPB) ? cnt[tid] : 0;
    if (tid < NPB) pos[tid] = v;
    __syncthreads();
    for (int off = 1; off < NPB; off <<= 1) {
        int t = (tid < NPB && tid >= off) ? pos[tid - off] : 0;
        __syncthreads();
        if (tid < NPB) pos[tid] += t;
        __syncthreads();
    }
    if (tid < NPB) {
        int excl = pos[tid] - v;           // exclusive prefix within bucket
        cur[tid] = excl;                   // stage-local cursor
        int g = b * NPB + tid;
        if (g < n) {
            row_start[g] = e0 + excl;
            dis[g] = rsqrtf((float)(v + 1));   // in-degree + self-loop
        }
    }
    if (b == nb_total - 1 && tid == 0) row_start[n] = e1;
    __syncthreads();

    // scatter into LDS stage (node-sorted within bucket); overflow -> direct store
    for (int e = e0 + tid; e < e1; e += 512) {
        int p = binned[e];
        int r = atomicAdd(&cur[p >> SRC_BITS], 1);
        int val = p & SRC_MASK;
        if (r < STAGE_CAP) stage[r] = val;
        else binned2[e0 + r] = val;
    }
    __syncthreads();

    // coalesced write-out
    int lim = min(csz, STAGE_CAP);
    for (int i = tid; i < lim; i += 512) binned2[e0 + i] = stage[i];

    // fused h1 for this bucket's 256 nodes (thread = node, tid < NPB)
    if (tid < NPB) {
        int g = b * NPB + tid;
        if (g < n) {
            float di = rsqrtf((float)(cnt[tid] + 1));
            float xi[N_IN_F];
            const float4* xr = (const float4*)(x + (size_t)g * N_IN_F);
#pragma unroll
            for (int q = 0; q < N_IN_F / 4; ++q) {
                float4 vv = xr[q];
                xi[4 * q + 0] = vv.x; xi[4 * q + 1] = vv.y;
                xi[4 * q + 2] = vv.z; xi[4 * q + 3] = vv.w;
            }
            __half2 hp[N_HID / 2];
#pragma unroll
            for (int f2 = 0; f2 < N_HID / 2; ++f2) {
                float ha = 0.0f, hb = 0.0f;
#pragma unroll
                for (int k = 0; k < N_IN_F; ++k) {
                    ha = fmaf(xi[k], w[k * N_HID + 2 * f2], ha);
                    hb = fmaf(xi[k], w[k * N_HID + 2 * f2 + 1], hb);
                }
                hp[f2] = __floats2half2_rn(ha * di, hb * di);
            }
            int4* dstp = (int4*)(hs1 + (size_t)g * N_HID);
            dstp[0] = *(const int4*)&hp[0];
            dstp[1] = *(const int4*)&hp[4];
        }
    }
}

// ---------------- compute ----------------

// SINGLE-PASS aggregation: 8 lanes per node (half2 per lane), 16-deep unrolled gather;
// fused relu + W2 + cross-lane reduce -> hs2 (fp32).
__global__ void __launch_bounds__(256)
k_agg1(const int* __restrict__ row_start, const int* __restrict__ esrc,
       const __half2* __restrict__ hs1, const float* __restrict__ dis,
       const float* __restrict__ b1, const float* __restrict__ W2,
       float2* __restrict__ hs2, int n) {
    int t = blockIdx.x * blockDim.x + threadIdx.x;
    int node = t >> 3;
    int f2 = t & 7;
    if (node >= n) return;

    int beg = row_start[node];
    int end = row_start[node + 1];
    const __half2* H = hs1 + f2;           // H[s*8] = features {2f2,2f2+1} of node s

    float2 sl = __half22float2(H[node * 8]);   // self-loop seed
    float ax = sl.x, ay = sl.y;
    float a0x = 0.f, a0y = 0.f, a1x = 0.f, a1y = 0.f;
    float a2x = 0.f, a2y = 0.f, a3x = 0.f, a3y = 0.f;
    int j = beg;
    for (; j + 16 <= end; j += 16) {
        int s[16];
#pragma unroll
        for (int q = 0; q < 16; ++q) s[q] = esrc[j + q];
        float2 v[16];
#pragma unroll
        for (int q = 0; q < 16; ++q) v[q] = __half22float2(H[s[q] * 8]);
#pragma unroll
        for (int q = 0; q < 16; q += 4) {
            a0x += v[q + 0].x; a0y += v[q + 0].y;
            a1x += v[q + 1].x; a1y += v[q + 1].y;
            a2x += v[q + 2].x; a2y += v[q + 2].y;
            a3x += v[q + 3].x; a3y += v[q + 3].y;
        }
    }
    for (; j + 4 <= end; j += 4) {
        int s0 = esrc[j], s1 = esrc[j + 1], s2 = esrc[j + 2], s3 = esrc[j + 3];
        float2 v0 = __half22float2(H[s0 * 8]);
        float2 v1 = __half22float2(H[s1 * 8]);
        float2 v2 = __half22float2(H[s2 * 8]);
        float2 v3 = __half22float2(H[s3 * 8]);
        a0x += v0.x; a0y += v0.y; a1x += v1.x; a1y += v1.y;
        a2x += v2.x; a2y += v2.y; a3x += v3.x; a3y += v3.y;
    }
    for (; j < end; ++j) {
        float2 v0 = __half22float2(H[esrc[j] * 8]);
        ax += v0.x; ay += v0.y;
    }
    ax += (a0x + a1x) + (a2x + a3x);
    ay += (a0y + a1y) + (a2y + a3y);

    float di = dis[node];
    float vx = fmaxf(fmaf(di, ax, b1[2 * f2 + 0]), 0.0f);
    float vy = fmaxf(fmaf(di, ay, b1[2 * f2 + 1]), 0.0f);
    float c0 = vx * W2[4 * f2 + 0] + vy * W2[4 * f2 + 2];
    float c1 = vx * W2[4 * f2 + 1] + vy * W2[4 * f2 + 3];
#pragma unroll
    for (int off = 4; off > 0; off >>= 1) {
        c0 += __shfl_xor(c0, off, 8);
        c1 += __shfl_xor(c1, off, 8);
    }
    if (f2 == 0) {
        float2 o;
        o.x = c0 * di;
        o.y = c1 * di;
        hs2[node] = o;
    }
}

// 4 lanes per node, 8-deep batched gather of hs2 (float2, L2-resident) + fused log_softmax
__global__ void __launch_bounds__(256)
k_agg2(const int* __restrict__ row_start, const int* __restrict__ esrc,
       const float2* __restrict__ hs2, const float* __restrict__ dis,
       const float* __restrict__ b2, float2* __restrict__ out, int n) {
    int t = blockIdx.x * blockDim.x + threadIdx.x;
    int node = t >> 2;
    int l = t & 3;
    if (node >= n) return;

    int beg = row_start[node];
    int end = row_start[node + 1];
    float cx = 0.f, cy = 0.f;
    int j = beg + l;
    for (; j + 28 < end; j += 32) {       // 8 indices: j, j+4, ..., j+28
        int s[8];
#pragma unroll
        for (int q = 0; q < 8; ++q) s[q] = esrc[j + 4 * q];
        float2 v[8];
#pragma unroll
        for (int q = 0; q < 8; ++q) v[q] = hs2[s[q]];
#pragma unroll
        for (int q = 0; q < 8; ++q) { cx += v[q].x; cy += v[q].y; }
    }
    for (; j < end; j += 4) {
        float2 v = hs2[esrc[j]];
        cx += v.x; cy += v.y;
    }
#pragma unroll
    for (int off = 2; off > 0; off >>= 1) {
        cx += __shfl_xor(cx, off, 4);
        cy += __shfl_xor(cy, off, 4);
    }
    if (l == 0) {
        float2 self = hs2[node];
        float di = dis[node];
        float a = fmaf(di, cx + self.x, b2[0]);
        float c = fmaf(di, cy + self.y, b2[1]);
        float m = fmaxf(a, c);
        float lse = m + logf(expf(a - m) + expf(c - m));
        float2 o;
        o.x = a - lse;
        o.y = c - lse;
        out[node] = o;
    }
}

// ---------------- launch ----------------

extern "C" void kernel_launch(void* const* d_in, const int* in_sizes, int n_in,
                              void* d_out, int out_size, void* d_ws, size_t ws_size,
                              hipStream_t stream) {
    const float* x  = (const float*)d_in[0];
    const int*   ei = (const int*)d_in[1];
    const float* W1 = (const float*)d_in[2];
    const float* b1 = (const float*)d_in[3];
    const float* W2 = (const float*)d_in[4];
    const float* b2 = (const float*)d_in[5];
    float2* out = (float2*)d_out;

    const int n  = in_sizes[0] / N_IN_F;   // 200000
    const int ne = in_sizes[1] / 2;        // 6400000
    const int* src = ei;
    const int* dst = ei + ne;
    const int nb = (n + NPB - 1) / NPB;    // 782 <= 1024
    const int nchunk = (ne + EPB - 1) / EPB;  // 782

    // workspace layout (4B units), total ~60MB. Aliasing (ordering-safe):
    //   gdelta (nchunk*NBK ints) aliases binned2 (dead before k_sort2 writes binned2)
    //   chunk_hist, hs1 are STANDALONE
    int* ws_i = (int*)d_ws;
    int* total     = ws_i;                      // 1024
    int* base      = total + 1024;              // 1028 (NBK+1 used)
    int* row_start = base + 1028;               // n+4
    float* dis     = (float*)(row_start + n + 4);  // n
    float2* hs2    = (float2*)(dis + n);        // n float2 (2n floats)
    __half* hs1    = (__half*)(hs2 + n);        // 16n halfs = 8n ints
    unsigned short* chunk_hist = (unsigned short*)((int*)hs1 + 8 * (size_t)n);  // nchunk*NBK u16
    int* binned2   = (int*)chunk_hist + ((size_t)nchunk * NBK + 1) / 2;  // ne
    int* binned    = binned2 + ne;              // ne
    int* gdelta    = binned2;                   // alias (nchunk*NBK ints <= ne)

    const int B = 256;

    k_bhist<<<dim3(nchunk), dim3(512), 0, stream>>>(dst, chunk_hist, ne);
    k_colscan<<<dim3(NBK / 16), dim3(B), 0, stream>>>(chunk_hist, gdelta, total, nchunk);
    k_top<<<dim3(1), dim3(NBK), 0, stream>>>(total, base, ne);
    k_bin<<<dim3(nchunk), dim3(1024), 0, stream>>>(src, dst, chunk_hist, gdelta, base, binned, ne);
    k_sort2<<<dim3(nb), dim3(512), 0, stream>>>(base, binned, binned2, row_start, dis,
                                                x, W1, hs1, n, nb);
    {
        long long tot = (long long)n * 8;
        k_agg1<<<dim3((unsigned)((tot + B - 1) / B)), dim3(B), 0, stream>>>(
            row_start, binned2, (const __half2*)hs1, dis, b1, W2, hs2, n);
    }
    {
        long long tot = (long long)n * 4;
        k_agg2<<<dim3((unsigned)((tot + B - 1) / B)), dim3(B), 0, stream>>>(
            row_start, binned2, hs2, dis, b2, out, n);
    }
}

// Round 20
// 173.718 us; speedup vs baseline: 1.2071x; 1.0380x over previous
//
#include <hip/hip_runtime.h>
#include <hip/hip_fp16.h>
#include <math.h>

#define N_IN_F 28
#define N_HID 16
#define NPB 256              // nodes per dst-bucket (bucket = dst >> 8)
#define NBK 1024             // bucket table size (782 actual)
#define EPB 8192             // edges per chunk (bhist/bin blocks)
#define SRC_BITS 18
#define SRC_MASK ((1 << SRC_BITS) - 1)
#define STAGE_CAP 10240      // LDS stage entries for k_sort2 (bucket mean 8192, sigma ~90)

// ---------------- build: chunk histograms -> column scans -> staged bin -> staged sort+h1 ----------------

// chunk histogram of dst>>8, saved to global (u16, coalesced). No global atomics.
__global__ void __launch_bounds__(1024)
k_bhist(const int* __restrict__ dst, unsigned short* __restrict__ chunk_hist, int ne) {
    __shared__ int hist[NBK];
    int tid = threadIdx.x;
    if (tid < NBK) hist[tid] = 0;
    __syncthreads();
    int e0 = blockIdx.x * EPB;
    int e1 = min(e0 + EPB, ne);
    for (int e = e0 + tid; e < e1; e += 1024) atomicAdd(&hist[dst[e] >> 8], 1);
    __syncthreads();
    unsigned short* ch = chunk_hist + (size_t)blockIdx.x * NBK;
    if (tid < NBK) ch[tid] = (unsigned short)hist[tid];
}

// 64 blocks x 16 buckets: per-bucket exclusive scan across chunks -> gdelta[chunk][bucket],
// plus per-bucket totals.
__global__ void __launch_bounds__(256)
k_colscan(const unsigned short* __restrict__ chunk_hist, int* __restrict__ gdelta,
          int* __restrict__ total, int nchunk) {
    __shared__ int p[16][17];
    int tid = threadIdx.x;
    int j = tid & 15;              // bucket lane within block's 16 buckets
    int g = tid >> 4;              // chunk-group
    int bkt = blockIdx.x * 16 + j;
    int cpg = (nchunk + 15) >> 4;
    int c0 = g * cpg, c1 = min(c0 + cpg, nchunk);

    int s = 0;
    for (int c = c0; c < c1; ++c) s += chunk_hist[(size_t)c * NBK + bkt];
    p[g][j] = s;
    __syncthreads();

    if (tid < 16) {                // serial scan over 16 groups for bucket tid
        int run = 0;
#pragma unroll
        for (int gg = 0; gg < 16; ++gg) { int t = p[gg][tid]; p[gg][tid] = run; run += t; }
        total[blockIdx.x * 16 + tid] = run;
    }
    __syncthreads();

    int run = p[g][j];
    for (int c = c0; c < c1; ++c) {
        int h = chunk_hist[(size_t)c * NBK + bkt];
        gdelta[(size_t)c * NBK + bkt] = run;
        run += h;
    }
}

// single block of 1024: exclusive scan of total -> base (+ sentinel)
__global__ void k_top(const int* __restrict__ total, int* __restrict__ base, int ne) {
    __shared__ int sm[NBK];
    int tid = threadIdx.x;
    int v = total[tid];
    sm[tid] = v;
    __syncthreads();
    for (int off = 1; off < NBK; off <<= 1) {
        int t = (tid >= off) ? sm[tid - off] : 0;
        __syncthreads();
        sm[tid] += t;
        __syncthreads();
    }
    base[tid] = sm[tid] - v;
    if (tid == 0) base[NBK] = ne;
}

// staged bin, 1024 threads (1 bucket/thread, 8 edges/thread): positions precomputed,
// wave-shuffle scan (3 barriers), 4B stage + u16 sbid side-table (O(1) write-out).
__global__ void __launch_bounds__(1024)
k_bin(const int* __restrict__ src, const int* __restrict__ dst,
      const unsigned short* __restrict__ chunk_hist, const int* __restrict__ gdelta,
      const int* __restrict__ base, int* __restrict__ binned, int ne) {
    __shared__ int gpos[NBK];
    __shared__ int lcur[NBK];
    __shared__ int wpart[16];
    __shared__ int stage[EPB];               // 32 KB
    __shared__ unsigned short sbid[EPB];     // 16 KB
    int tid = threadIdx.x;
    int lane = tid & 63;
    int wid = tid >> 6;                      // 0..15
    int chunk = blockIdx.x;

    // one bucket per thread: load hist value, block-scan via wave shuffles
    int h = chunk_hist[(size_t)chunk * NBK + tid];
    int val = h;
#pragma unroll
    for (int off = 1; off < 64; off <<= 1) {
        int t = __shfl_up(val, off, 64);
        if (lane >= off) val += t;
    }
    if (lane == 63) wpart[wid] = val;
    __syncthreads();
    if (wid == 0) {
        int p = (lane < 16) ? wpart[lane] : 0;
#pragma unroll
        for (int off = 1; off < 16; off <<= 1) {
            int t = __shfl_up(p, off, 64);
            if (lane >= off) p += t;
        }
        if (lane < 16) wpart[lane] = p;      // inclusive over waves
    }
    __syncthreads();
    int wbase = (wid > 0) ? wpart[wid - 1] : 0;
    int excl = wbase + val - h;              // exclusive prefix = local base
    gpos[tid] = base[tid] + gdelta[(size_t)chunk * NBK + tid] - excl;
    lcur[tid] = excl;
    __syncthreads();

    int e0 = chunk * EPB;
    int csz = min(EPB, ne - e0);

    // local scatter into LDS stage (bucket-sorted within chunk), 4B + 2B per edge
    for (int i = tid; i < csz; i += 1024) {
        int d = dst[e0 + i];
        int b = d >> 8;
        int r = atomicAdd(&lcur[b], 1);
        stage[r] = src[e0 + i] | ((d & (NPB - 1)) << SRC_BITS);
        sbid[r] = (unsigned short)b;
    }
    __syncthreads();

    // coalesced write-out: O(1) bucket lookup via sbid
    for (int i = tid; i < csz; i += 1024) {
        binned[gpos[sbid[i]] + i] = stage[i];
    }
}

// block per dst-bucket, 1024 threads (8 edges/thread): counting sort by dst-local index,
// wave-shuffle scan (3 barriers), STAGED in LDS for coalesced write-out ->
// node-contiguous binned2 (plain src), row_start[], dis[];
// FUSED h1 (4 threads/node x 4 features): hs1 = fp16((x@W1)*dis), interleaved 32B rows.
__global__ void __launch_bounds__(1024)
k_sort2(const int* __restrict__ base, const int* __restrict__ binned,
        int* __restrict__ binned2, int* __restrict__ row_start,
        float* __restrict__ dis, const float* __restrict__ x,
        const float* __restrict__ W1, __half* __restrict__ hs1,
        int n, int nb_total) {
    __shared__ int cnt[NPB];
    __shared__ int cur[NPB];
    __shared__ int wpart[4];
    __shared__ float w[N_IN_F * N_HID];
    __shared__ int stage[STAGE_CAP];         // 40 KB
    int tid = threadIdx.x;
    int lane = tid & 63;
    int wv = tid >> 6;
    if (tid < NPB) cnt[tid] = 0;
    if (tid < N_IN_F * N_HID) w[tid] = W1[tid];
    __syncthreads();

    int b = blockIdx.x;
    int e0 = base[b], e1 = base[b + 1];
    int csz = e1 - e0;

    for (int e = e0 + tid; e < e1; e += 1024) atomicAdd(&cnt[binned[e] >> SRC_BITS], 1);
    __syncthreads();

    // scan 256 counters with waves 0..3 via shuffles
    int deg = 0, incl = 0;
    if (tid < NPB) {
        deg = cnt[tid];
        incl = deg;
#pragma unroll
        for (int off = 1; off < 64; off <<= 1) {
            int t = __shfl_up(incl, off, 64);
            if (lane >= off) incl += t;
        }
        if (lane == 63) wpart[wv] = incl;
    }
    __syncthreads();
    if (tid < NPB) {
        int wbase = 0;
#pragma unroll
        for (int q = 0; q < 4; ++q) wbase += (q < wv) ? wpart[q] : 0;
        int excl = wbase + incl - deg;       // exclusive prefix within bucket
        cur[tid] = excl;                     // stage-local cursor
        int g = b * NPB + tid;
        if (g < n) {
            row_start[g] = e0 + excl;
            dis[g] = rsqrtf((float)(deg + 1));   // in-degree + self-loop
        }
    }
    if (b == nb_total - 1 && tid == 0) row_start[n] = e1;
    __syncthreads();

    // scatter into LDS stage (node-sorted within bucket); overflow -> direct store
    for (int e = e0 + tid; e < e1; e += 1024) {
        int p = binned[e];
        int r = atomicAdd(&cur[p >> SRC_BITS], 1);
        int val = p & SRC_MASK;
        if (r < STAGE_CAP) stage[r] = val;
        else binned2[e0 + r] = val;
    }
    __syncthreads();

    // coalesced write-out
    int lim = min(csz, STAGE_CAP);
    for (int i = tid; i < lim; i += 1024) binned2[e0 + i] = stage[i];

    // fused h1: 4 threads per node, 4 features each (all 1024 threads active).
    // x-row reads broadcast across the 4 lanes; int2 stores coalesce to 32B/node.
    {
        int ln = tid >> 2;                   // local node 0..255
        int fq = tid & 3;                    // feature quad 0..3
        int g = b * NPB + ln;
        if (g < n) {
            float di = rsqrtf((float)(cnt[ln] + 1));
            float xi[N_IN_F];
            const float4* xr = (const float4*)(x + (size_t)g * N_IN_F);
#pragma unroll
            for (int q = 0; q < N_IN_F / 4; ++q) {
                float4 vv = xr[q];
                xi[4 * q + 0] = vv.x; xi[4 * q + 1] = vv.y;
                xi[4 * q + 2] = vv.z; xi[4 * q + 3] = vv.w;
            }
            __half2 hp[2];
#pragma unroll
            for (int h2i = 0; h2i < 2; ++h2i) {
                int f = 4 * fq + 2 * h2i;
                float ha = 0.0f, hb = 0.0f;
#pragma unroll
                for (int k = 0; k < N_IN_F; ++k) {
                    ha = fmaf(xi[k], w[k * N_HID + f], ha);
                    hb = fmaf(xi[k], w[k * N_HID + f + 1], hb);
                }
                hp[h2i] = __floats2half2_rn(ha * di, hb * di);
            }
            int2 o;
            o.x = *(const int*)&hp[0];
            o.y = *(const int*)&hp[1];
            ((int2*)(hs1 + (size_t)g * N_HID))[fq] = o;
        }
    }
}

// ---------------- compute ----------------

// SINGLE-PASS aggregation: 8 lanes per node (half2 per lane), 16-deep unrolled gather;
// fused relu + W2 + cross-lane reduce -> hs2 (fp32).
__global__ void __launch_bounds__(256)
k_agg1(const int* __restrict__ row_start, const int* __restrict__ esrc,
       const __half2* __restrict__ hs1, const float* __restrict__ dis,
       const float* __restrict__ b1, const float* __restrict__ W2,
       float2* __restrict__ hs2, int n) {
    int t = blockIdx.x * blockDim.x + threadIdx.x;
    int node = t >> 3;
    int f2 = t & 7;
    if (node >= n) return;

    int beg = row_start[node];
    int end = row_start[node + 1];
    const __half2* H = hs1 + f2;           // H[s*8] = features {2f2,2f2+1} of node s

    float2 sl = __half22float2(H[node * 8]);   // self-loop seed
    float ax = sl.x, ay = sl.y;
    float a0x = 0.f, a0y = 0.f, a1x = 0.f, a1y = 0.f;
    float a2x = 0.f, a2y = 0.f, a3x = 0.f, a3y = 0.f;
    int j = beg;
    for (; j + 16 <= end; j += 16) {
        int s[16];
#pragma unroll
        for (int q = 0; q < 16; ++q) s[q] = esrc[j + q];
        float2 v[16];
#pragma unroll
        for (int q = 0; q < 16; ++q) v[q] = __half22float2(H[s[q] * 8]);
#pragma unroll
        for (int q = 0; q < 16; q += 4) {
            a0x += v[q + 0].x; a0y += v[q + 0].y;
            a1x += v[q + 1].x; a1y += v[q + 1].y;
            a2x += v[q + 2].x; a2y += v[q + 2].y;
            a3x += v[q + 3].x; a3y += v[q + 3].y;
        }
    }
    for (; j + 4 <= end; j += 4) {
        int s0 = esrc[j], s1 = esrc[j + 1], s2 = esrc[j + 2], s3 = esrc[j + 3];
        float2 v0 = __half22float2(H[s0 * 8]);
        float2 v1 = __half22float2(H[s1 * 8]);
        float2 v2 = __half22float2(H[s2 * 8]);
        float2 v3 = __half22float2(H[s3 * 8]);
        a0x += v0.x; a0y += v0.y; a1x += v1.x; a1y += v1.y;
        a2x += v2.x; a2y += v2.y; a3x += v3.x; a3y += v3.y;
    }
    for (; j < end; ++j) {
        float2 v0 = __half22float2(H[esrc[j] * 8]);
        ax += v0.x; ay += v0.y;
    }
    ax += (a0x + a1x) + (a2x + a3x);
    ay += (a0y + a1y) + (a2y + a3y);

    float di = dis[node];
    float vx = fmaxf(fmaf(di, ax, b1[2 * f2 + 0]), 0.0f);
    float vy = fmaxf(fmaf(di, ay, b1[2 * f2 + 1]), 0.0f);
    float c0 = vx * W2[4 * f2 + 0] + vy * W2[4 * f2 + 2];
    float c1 = vx * W2[4 * f2 + 1] + vy * W2[4 * f2 + 3];
#pragma unroll
    for (int off = 4; off > 0; off >>= 1) {
        c0 += __shfl_xor(c0, off, 8);
        c1 += __shfl_xor(c1, off, 8);
    }
    if (f2 == 0) {
        float2 o;
        o.x = c0 * di;
        o.y = c1 * di;
        hs2[node] = o;
    }
}

// 4 lanes per node, 8-deep batched gather of hs2 (float2, L2-resident) + fused log_softmax
__global__ void __launch_bounds__(256)
k_agg2(const int* __restrict__ row_start, const int* __restrict__ esrc,
       const float2* __restrict__ hs2, const float* __restrict__ dis,
       const float* __restrict__ b2, float2* __restrict__ out, int n) {
    int t = blockIdx.x * blockDim.x + threadIdx.x;
    int node = t >> 2;
    int l = t & 3;
    if (node >= n) return;

    int beg = row_start[node];
    int end = row_start[node + 1];
    float cx = 0.f, cy = 0.f;
    int j = beg + l;
    for (; j + 28 < end; j += 32) {       // 8 indices: j, j+4, ..., j+28
        int s[8];
#pragma unroll
        for (int q = 0; q < 8; ++q) s[q] = esrc[j + 4 * q];
        float2 v[8];
#pragma unroll
        for (int q = 0; q < 8; ++q) v[q] = hs2[s[q]];
#pragma unroll
        for (int q = 0; q < 8; ++q) { cx += v[q].x; cy += v[q].y; }
    }
    for (; j < end; j += 4) {
        float2 v = hs2[esrc[j]];
        cx += v.x; cy += v.y;
    }
#pragma unroll
    for (int off = 2; off > 0; off >>= 1) {
        cx += __shfl_xor(cx, off, 4);
        cy += __shfl_xor(cy, off, 4);
    }
    if (l == 0) {
        float2 self = hs2[node];
        float di = dis[node];
        float a = fmaf(di, cx + self.x, b2[0]);
        float c = fmaf(di, cy + self.y, b2[1]);
        float m = fmaxf(a, c);
        float lse = m + logf(expf(a - m) + expf(c - m));
        float2 o;
        o.x = a - lse;
        o.y = c - lse;
        out[node] = o;
    }
}

// ---------------- launch ----------------

extern "C" void kernel_launch(void* const* d_in, const int* in_sizes, int n_in,
                              void* d_out, int out_size, void* d_ws, size_t ws_size,
                              hipStream_t stream) {
    const float* x  = (const float*)d_in[0];
    const int*   ei = (const int*)d_in[1];
    const float* W1 = (const float*)d_in[2];
    const float* b1 = (const float*)d_in[3];
    const float* W2 = (const float*)d_in[4];
    const float* b2 = (const float*)d_in[5];
    float2* out = (float2*)d_out;

    const int n  = in_sizes[0] / N_IN_F;   // 200000
    const int ne = in_sizes[1] / 2;        // 6400000
    const int* src = ei;
    const int* dst = ei + ne;
    const int nb = (n + NPB - 1) / NPB;    // 782 <= 1024
    const int nchunk = (ne + EPB - 1) / EPB;  // 782

    // workspace layout (4B units), total ~60MB. Aliasing (ordering-safe):
    //   gdelta (nchunk*NBK ints) aliases binned2 (dead before k_sort2 writes binned2)
    //   chunk_hist, hs1 are STANDALONE
    int* ws_i = (int*)d_ws;
    int* total     = ws_i;                      // 1024
    int* base      = total + 1024;              // 1028 (NBK+1 used)
    int* row_start = base + 1028;               // n+4
    float* dis     = (float*)(row_start + n + 4);  // n
    float2* hs2    = (float2*)(dis + n);        // n float2 (2n floats)
    __half* hs1    = (__half*)(hs2 + n);        // 16n halfs = 8n ints
    unsigned short* chunk_hist = (unsigned short*)((int*)hs1 + 8 * (size_t)n);  // nchunk*NBK u16
    int* binned2   = (int*)chunk_hist + ((size_t)nchunk * NBK + 1) / 2;  // ne
    int* binned    = binned2 + ne;              // ne
    int* gdelta    = binned2;                   // alias (nchunk*NBK ints <= ne)

    const int B = 256;

    k_bhist<<<dim3(nchunk), dim3(1024), 0, stream>>>(dst, chunk_hist, ne);
    k_colscan<<<dim3(NBK / 16), dim3(B), 0, stream>>>(chunk_hist, gdelta, total, nchunk);
    k_top<<<dim3(1), dim3(NBK), 0, stream>>>(total, base, ne);
    k_bin<<<dim3(nchunk), dim3(1024), 0, stream>>>(src, dst, chunk_hist, gdelta, base, binned, ne);
    k_sort2<<<dim3(nb), dim3(1024), 0, stream>>>(base, binned, binned2, row_start, dis,
                                                 x, W1, hs1, n, nb);
    {
        long long tot = (long long)n * 8;
        k_agg1<<<dim3((unsigned)((tot + B - 1) / B)), dim3(B), 0, stream>>>(
            row_start, binned2, (const __half2*)hs1, dis, b1, W2, hs2, n);
    }
    {
        long long tot = (long long)n * 4;
        k_agg2<<<dim3((unsigned)((tot + B - 1) / B)), dim3(B), 0, stream>>>(
            row_start, binned2, hs2, dis, b2, out, n);
    }
}